// Round 10
// baseline (296.882 us; speedup 1.0000x reference)
//
#include <hip/hip_runtime.h>
#include <math.h>

#define NB 4
#define C_ 256
#define NG 8
#define CPG 32
#define HW 4096
#define NH 4
#define HD 64
#define EPS 1e-5f
#define QSCALE 0.1803368801111204f  /* 0.125 * log2(e): folds 1/sqrt(64) and base-2 softmax */

typedef __attribute__((ext_vector_type(8))) short bf16x8_t;
typedef __attribute__((ext_vector_type(4))) float f32x4_t;
typedef const __attribute__((address_space(1))) void g_void;
typedef __attribute__((address_space(3))) void l_void;

__device__ __forceinline__ unsigned short f2bf(float f) {
    unsigned u = __float_as_uint(f);
    u += 0x7FFFu + ((u >> 16) & 1u);   // RNE
    return (unsigned short)(u >> 16);
}

// ---------------- weight conversion: w_qkv + w_proj -> bf16 ----------------
__global__ __launch_bounds__(256) void wconv_k(const float* __restrict__ wq,
                                               const float* __restrict__ wp,
                                               unsigned short* __restrict__ wt,
                                               unsigned short* __restrict__ wpt) {
    int i4 = blockIdx.x * 256 + threadIdx.x;   // 0..65535 float4 groups
    const float* src;
    unsigned short* dst;
    int off;
    if (i4 < 49152) { src = wq; dst = wt; off = i4 * 4; }
    else            { src = wp; dst = wpt; off = (i4 - 49152) * 4; }
    float4 v = *(const float4*)(src + off);
    ushort4 o;
    o.x = f2bf(v.x); o.y = f2bf(v.y); o.z = f2bf(v.z); o.w = f2bf(v.w);
    *(ushort4*)(dst + off) = o;
}

// ---------------- GroupNorm stats, phase A: 32 chunks per (b,g) group ----------------
__global__ __launch_bounds__(256) void gn_stats_part_k(const float* __restrict__ x,
                                                       float2* __restrict__ part) {
    int bg = blockIdx.x >> 5, ch = blockIdx.x & 31;
    const float4* base = (const float4*)(x + (size_t)bg * CPG * HW + ch * 4096);
    float s = 0.f, ss = 0.f;
    #pragma unroll
    for (int i = threadIdx.x; i < 1024; i += 256) {
        float4 v = base[i];
        s  += v.x + v.y + v.z + v.w;
        ss += v.x*v.x + v.y*v.y + v.z*v.z + v.w*v.w;
    }
    #pragma unroll
    for (int off = 32; off > 0; off >>= 1) {
        s  += __shfl_down(s, off);
        ss += __shfl_down(ss, off);
    }
    __shared__ float rs[4], rss[4];
    int wv = threadIdx.x >> 6;
    if ((threadIdx.x & 63) == 0) { rs[wv] = s; rss[wv] = ss; }
    __syncthreads();
    if (threadIdx.x == 0)
        part[blockIdx.x] = make_float2(rs[0]+rs[1]+rs[2]+rs[3], rss[0]+rss[1]+rss[2]+rss[3]);
}

// ---------------- GroupNorm stats, phase B: finalize 32 groups ----------------
__global__ __launch_bounds__(64) void gn_stats_fin_k(const float2* __restrict__ part,
                                                     float* __restrict__ stats) {
    int t = threadIdx.x;
    if (t < 32) {
        float s = 0.f, ss = 0.f;
        #pragma unroll
        for (int c = 0; c < 32; c++) { float2 v = part[t * 32 + c]; s += v.x; ss += v.y; }
        const float inv = 1.f / (float)(CPG * HW);
        float mean = s * inv;
        float var  = ss * inv - mean * mean;
        stats[2*t]   = mean;
        stats[2*t+1] = rsqrtf(var + EPS);
    }
}

// ---------------- FUSED GroupNorm-apply + QKV GEMM (bf16 MFMA) ----------------
// One block per (p-tile 64, b). Phase 1: load x[b][:][p-tile], normalize, store h^T
// tile to LDS [p][c] bf16 with XOR-swizzled 16B chunks (slot = (c>>3)^(p&7)) ->
// even bank spread for both scalar writes and b128 fragment reads. Phase 2: loop
// all 12 m-tiles of wt against the LDS tile (A streamed from global/L2, k-contig).
// Eliminates the ht global round-trip and the separate apply kernel entirely.
__global__ __launch_bounds__(256) void gemm_qkv_fused_k(const unsigned short* __restrict__ wt,
                                                        const float* __restrict__ x,
                                                        const float* __restrict__ gamma,
                                                        const float* __restrict__ beta,
                                                        const float* __restrict__ stats,
                                                        const float* __restrict__ bias,
                                                        unsigned short* __restrict__ qt,
                                                        unsigned short* __restrict__ kt,
                                                        unsigned short* __restrict__ vv) {
    __shared__ __align__(16) unsigned short T[64 * 256];   // 32KB, [p][c] swizzled
    int b = blockIdx.y, p0 = blockIdx.x * 64;
    int t = threadIdx.x;
    // phase 1
    {
        int cr = t >> 4, pc = t & 15;
        #pragma unroll
        for (int ct = 0; ct < 4; ct++)
            #pragma unroll
            for (int cp = 0; cp < 4; cp++) {
                int c = ct * 64 + cp * 16 + cr;
                int bg = b * NG + (c >> 5);
                float mean = stats[2*bg], rstd = stats[2*bg+1];
                float sc = gamma[c] * rstd;
                float sh = beta[c] - mean * sc;
                float4 v = *(const float4*)(x + ((size_t)(b * C_ + c)) * HW + p0 + pc * 4);
                float vals[4] = {v.x, v.y, v.z, v.w};
                #pragma unroll
                for (int k = 0; k < 4; k++) {
                    int p = pc * 4 + k;
                    T[p * 256 + (((c >> 3) ^ (p & 7)) * 8) + (c & 7)] = f2bf(vals[k] * sc + sh);
                }
            }
    }
    __syncthreads();
    // phase 2
    int wave = t >> 6, lane = t & 63, quad = lane >> 4, l16 = lane & 15;
    int mw = wave & 1, pw = wave >> 1;
    const f32x4_t zz = {0.f, 0.f, 0.f, 0.f};
    for (int my = 0; my < 12; my++) {
        const unsigned short* Ab = wt + (size_t)(my * 64 + mw * 32) * 256;
        f32x4_t acc[2][2];
        acc[0][0] = zz; acc[0][1] = zz; acc[1][0] = zz; acc[1][1] = zz;
        #pragma unroll
        for (int kc = 0; kc < 8; kc++) {
            bf16x8_t af[2], bfr[2];
            #pragma unroll
            for (int mi = 0; mi < 2; mi++)
                af[mi] = *(const bf16x8_t*)(Ab + (mi*16 + l16) * 256 + kc*32 + quad*8);
            #pragma unroll
            for (int pi = 0; pi < 2; pi++) {
                int p = pw*32 + pi*16 + l16;
                bfr[pi] = *(const bf16x8_t*)&T[p * 256 + (((kc*4 + quad) ^ (p & 7)) * 8)];
            }
            #pragma unroll
            for (int mi = 0; mi < 2; mi++)
                #pragma unroll
                for (int pi = 0; pi < 2; pi++)
                    acc[mi][pi] = __builtin_amdgcn_mfma_f32_16x16x32_bf16(af[mi], bfr[pi], acc[mi][pi], 0, 0, 0);
        }
        int sec = my >> 2, hh = my & 3;
        if (sec < 2) {
            float scl = (sec == 0) ? QSCALE : 1.f;
            unsigned short* dst = ((sec == 0) ? qt : kt) + (size_t)(b * NH + hh) * HW * 64;
            #pragma unroll
            for (int mi = 0; mi < 2; mi++) {
                int d0 = mw*32 + mi*16 + quad*4;
                #pragma unroll
                for (int pi = 0; pi < 2; pi++) {
                    int p = p0 + pw*32 + pi*16 + l16;
                    ushort4 o;
                    o.x = f2bf((acc[mi][pi][0] + bias[my*64 + d0 + 0]) * scl);
                    o.y = f2bf((acc[mi][pi][1] + bias[my*64 + d0 + 1]) * scl);
                    o.z = f2bf((acc[mi][pi][2] + bias[my*64 + d0 + 2]) * scl);
                    o.w = f2bf((acc[mi][pi][3] + bias[my*64 + d0 + 3]) * scl);
                    *(ushort4*)(dst + (size_t)p * 64 + d0) = o;
                }
            }
        } else {
            unsigned short* dst = vv + (size_t)(b * NH + hh) * 64 * HW;
            #pragma unroll
            for (int mi = 0; mi < 2; mi++)
                #pragma unroll
                for (int pi = 0; pi < 2; pi++) {
                    int p = p0 + pw*32 + pi*16 + l16;
                    #pragma unroll
                    for (int r = 0; r < 4; r++) {
                        int d = mw*32 + mi*16 + quad*4 + r;
                        dst[(size_t)d * HW + p] = f2bf(acc[mi][pi][r] + bias[my*64 + d]);
                    }
                }
        }
    }
}

// ---------------- proj GEMM, bf16 MFMA, LDS-free; + bias + residual, fp32 out ----------------
__global__ __launch_bounds__(256) void gemm_proj_mfma_k(const unsigned short* __restrict__ wpt,
                                                        const unsigned short* __restrict__ ao,
                                                        const float* __restrict__ bias,
                                                        const float* __restrict__ x,
                                                        float* __restrict__ out) {
    int b = blockIdx.z, my = blockIdx.y, px = blockIdx.x;
    int t = threadIdx.x, wave = t >> 6, lane = t & 63, quad = lane >> 4, l16 = lane & 15;
    int mw = wave & 1, pw = wave >> 1;
    const unsigned short* Ab = wpt + (size_t)(my * 64 + mw * 32) * 256;
    const unsigned short* Bb = ao + ((size_t)b * HW + px * 64 + pw * 32) * 256;
    f32x4_t acc[2][2];
    const f32x4_t zz = {0.f, 0.f, 0.f, 0.f};
    acc[0][0] = zz; acc[0][1] = zz; acc[1][0] = zz; acc[1][1] = zz;
    #pragma unroll
    for (int kc = 0; kc < 8; kc++) {
        bf16x8_t af[2], bfr[2];
        #pragma unroll
        for (int mi = 0; mi < 2; mi++)
            af[mi] = *(const bf16x8_t*)(Ab + (mi*16 + l16) * 256 + kc*32 + quad*8);
        #pragma unroll
        for (int pi = 0; pi < 2; pi++)
            bfr[pi] = *(const bf16x8_t*)(Bb + (size_t)(pi*16 + l16) * 256 + kc*32 + quad*8);
        #pragma unroll
        for (int mi = 0; mi < 2; mi++)
            #pragma unroll
            for (int pi = 0; pi < 2; pi++)
                acc[mi][pi] = __builtin_amdgcn_mfma_f32_16x16x32_bf16(af[mi], bfr[pi], acc[mi][pi], 0, 0, 0);
    }
    #pragma unroll
    for (int mi = 0; mi < 2; mi++)
        #pragma unroll
        for (int pi = 0; pi < 2; pi++) {
            int p = px*64 + pw*32 + pi*16 + l16;
            #pragma unroll
            for (int r = 0; r < 4; r++) {
                int m = my*64 + mw*32 + mi*16 + quad*4 + r;
                size_t off = (size_t)(b * C_ + m) * HW + p;
                out[off] = acc[mi][pi][r] + bias[m] + x[off];
            }
        }
}

// ---------------- Flash attention, bf16 MFMA, i×j wave split ----------------
// qt,kt: [(b,h)][p][64] bf16 (Q pre-scaled); vv: [(b,h)][64][p] bf16.
// r10: K fragments load DIRECTLY from global (kt is [p][d], A-fragments are
// contiguous 16B — the r9 LDS staging swizzle round-tripped to identity), with a
// register prefetch (kfn) one tile ahead. Only V goes through LDS
// (global_load_lds width=16, double-buffered). LDS 34KB -> still 4 blocks/CU.
__global__ __launch_bounds__(256) __attribute__((amdgpu_waves_per_eu(2, 4)))
void attn_k(const unsigned short* __restrict__ qt,
            const unsigned short* __restrict__ kt,
            const unsigned short* __restrict__ vv,
            unsigned short* __restrict__ ao) {
    // ushort idx: V0 0..4095 | V1 4096..8191 | Pt 8192..12287; epilogue reuses as
    // Obuf (16640 ushorts) + ml (512) = 17152 <= 17408.
    __shared__ __align__(16) unsigned short smem[17408];  // 34KB
    unsigned short* Pt = smem + 8192;
    int t = threadIdx.x;
    int wave = t >> 6, lane = t & 63, quad = lane >> 4, l16 = lane & 15;
    int iw = wave & 1, jw = wave >> 1;
    int i0 = blockIdx.x * 64;
    int hh = blockIdx.y, b = blockIdx.z;
    const unsigned short* qb  = qt + (size_t)(b * NH + hh) * HW * 64;
    const unsigned short* kb16 = kt + (size_t)(b * NH + hh) * HW * 64;
    const char* vbp = (const char*)(vv + (size_t)(b * NH + hh) * 64 * HW);

    bf16x8_t qf[2][2];
    #pragma unroll
    for (int mi = 0; mi < 2; mi++)
        #pragma unroll
        for (int kc = 0; kc < 2; kc++)
            qf[mi][kc] = *(const bf16x8_t*)(qb + (size_t)(i0 + iw * 32 + mi * 16 + l16) * 64 + kc * 32 + quad * 8);

    f32x4_t oacc[4][2];
    const f32x4_t zz = {0.f, 0.f, 0.f, 0.f};
    #pragma unroll
    for (int dt = 0; dt < 4; dt++) { oacc[dt][0] = zz; oacc[dt][1] = zz; }
    float m_pr[2] = {-INFINITY, -INFINITY};
    float l_sum[2] = {0.f, 0.f};

    // V staging map (swizzled 16B chunks; deposit is wave-uniform base + lane*16)
    int soffV[2], ldsoff[2];
    #pragma unroll
    for (int n = 0; n < 2; n++) {
        int s = n * 256 + t;
        int row = s >> 3;
        int c = (s & 7) ^ (row & 7);
        soffV[n] = row * (HW * 2) + c * 16;     // bytes (row=d, stride HW*2)
        ldsoff[n] = n * 2048 + wave * 512;      // ushort idx within V tile
    }

    // preload: V tile 0 async; K tile 0 fragments direct
    #pragma unroll
    for (int n = 0; n < 2; n++)
        __builtin_amdgcn_global_load_lds((g_void*)(vbp + soffV[n]), (l_void*)(smem + ldsoff[n]), 16, 0, 0);
    bf16x8_t kf[2][2];
    #pragma unroll
    for (int nj = 0; nj < 2; nj++)
        #pragma unroll
        for (int kc = 0; kc < 2; kc++)
            kf[nj][kc] = *(const bf16x8_t*)(kb16 + (size_t)(jw * 32 + nj * 16 + l16) * 64 + kc * 32 + quad * 8);

    for (int jt = 0; jt < 64; jt++) {
        asm volatile("s_waitcnt vmcnt(0)" ::: "memory");
        asm volatile("s_barrier" ::: "memory");
        bf16x8_t kfn[2][2];
        if (jt < 63) {
            const char* vb = vbp + (size_t)(jt + 1) * 128;
            int bb = ((jt + 1) & 1) * 4096;
            #pragma unroll
            for (int n = 0; n < 2; n++)
                __builtin_amdgcn_global_load_lds((g_void*)(vb + soffV[n]), (l_void*)(smem + bb + ldsoff[n]), 16, 0, 0);
            const unsigned short* kb2 = kb16 + (size_t)(jt + 1) * 4096;
            #pragma unroll
            for (int nj = 0; nj < 2; nj++)
                #pragma unroll
                for (int kc = 0; kc < 2; kc++)
                    kfn[nj][kc] = *(const bf16x8_t*)(kb2 + (size_t)(jw * 32 + nj * 16 + l16) * 64 + kc * 32 + quad * 8);
        }
        const unsigned short* Vc = smem + (jt & 1) * 4096;

        // ---- S^T = K·Q^T on this wave's 32 j x 32 i ----
        f32x4_t sacc[2][2];
        sacc[0][0] = zz; sacc[0][1] = zz; sacc[1][0] = zz; sacc[1][1] = zz;
        #pragma unroll
        for (int nj = 0; nj < 2; nj++)
            #pragma unroll
            for (int mi = 0; mi < 2; mi++) {
                sacc[mi][nj] = __builtin_amdgcn_mfma_f32_16x16x32_bf16(kf[nj][0], qf[mi][0], sacc[mi][nj], 0, 0, 0);
                sacc[mi][nj] = __builtin_amdgcn_mfma_f32_16x16x32_bf16(kf[nj][1], qf[mi][1], sacc[mi][nj], 0, 0, 0);
            }

        // ---- online softmax (base-2) per i-tile; per-lane-replicated, j-half-local ----
        float alpha_[2];
        #pragma unroll
        for (int mi = 0; mi < 2; mi++) {
            float m = sacc[mi][0][0];
            #pragma unroll
            for (int nj = 0; nj < 2; nj++)
                #pragma unroll
                for (int r = 0; r < 4; r++) m = fmaxf(m, sacc[mi][nj][r]);
            m = fmaxf(m, __shfl_xor(m, 16));
            m = fmaxf(m, __shfl_xor(m, 32));
            float mnew = fmaxf(m_pr[mi], m);
            float a = __builtin_amdgcn_exp2f(m_pr[mi] - mnew);
            alpha_[mi] = a;
            float rs = 0.f;
            #pragma unroll
            for (int nj = 0; nj < 2; nj++)
                #pragma unroll
                for (int r = 0; r < 4; r++) {
                    float p = __builtin_amdgcn_exp2f(sacc[mi][nj][r] - mnew);
                    sacc[mi][nj][r] = p;
                    rs += p;
                }
            rs += __shfl_xor(rs, 16);
            rs += __shfl_xor(rs, 32);
            l_sum[mi] = l_sum[mi] * a + rs;
            m_pr[mi] = mnew;

            #pragma unroll
            for (int nj = 0; nj < 2; nj++) {
                unsigned lo = (unsigned)f2bf(sacc[mi][nj][0]) | ((unsigned)f2bf(sacc[mi][nj][1]) << 16);
                unsigned hi = (unsigned)f2bf(sacc[mi][nj][2]) | ((unsigned)f2bf(sacc[mi][nj][3]) << 16);
                int chunk = (nj * 2 + (quad >> 1)) * 16 + l16;
                *(uint2*)&Pt[((wave * 2 + mi) * 64 + chunk) * 8 + 4 * (quad & 1)] = make_uint2(lo, hi);
            }
        }

        #pragma unroll
        for (int dt = 0; dt < 4; dt++) { oacc[dt][0] *= alpha_[0]; oacc[dt][1] *= alpha_[1]; }

        asm volatile("" ::: "memory");   // wave-private P round-trip: compiler fence (r2/r7)

        bf16x8_t pf[2];
        pf[0] = *(const bf16x8_t*)&Pt[((wave * 2 + 0) * 64 + quad * 16 + l16) * 8];
        pf[1] = *(const bf16x8_t*)&Pt[((wave * 2 + 1) * 64 + quad * 16 + l16) * 8];
        #pragma unroll
        for (int dt = 0; dt < 4; dt++) {
            int d = dt * 16 + l16;
            bf16x8_t vf = *(const bf16x8_t*)&Vc[(d * 8 + ((jw * 4 + quad) ^ (d & 7))) * 8];
            oacc[dt][0] = __builtin_amdgcn_mfma_f32_16x16x32_bf16(vf, pf[0], oacc[dt][0], 0, 0, 0);
            oacc[dt][1] = __builtin_amdgcn_mfma_f32_16x16x32_bf16(vf, pf[1], oacc[dt][1], 0, 0, 0);
        }
        if (jt < 63) {
            #pragma unroll
            for (int nj = 0; nj < 2; nj++)
                #pragma unroll
                for (int kc = 0; kc < 2; kc++)
                    kf[nj][kc] = kfn[nj][kc];
        }
    }

    // ---- epilogue: all waves stage O^T + (m,l) in LDS; merge j-halves; bf16 [p][c] out ----
    __syncthreads();                           // all V/P consumption done; reuse smem
    float* Obuf = (float*)smem;                // [(iw*2+jw)*32 + i'][65] (d fast)
    float2* ml  = (float2*)(Obuf + 4 * 32 * 65);  // 128 entries
    int rowbase = (iw * 2 + jw) * 32;
    #pragma unroll
    for (int dt = 0; dt < 4; dt++)
        #pragma unroll
        for (int ni = 0; ni < 2; ni++)
            #pragma unroll
            for (int r = 0; r < 4; r++)
                Obuf[(rowbase + ni * 16 + l16) * 65 + dt * 16 + quad * 4 + r] = oacc[dt][ni][r];
    if (quad == 0) {
        ml[rowbase + l16]      = make_float2(m_pr[0], l_sum[0]);
        ml[rowbase + 16 + l16] = make_float2(m_pr[1], l_sum[1]);
    }
    __syncthreads();
    {
        int iloc = t >> 2, cq = t & 3;
        int iw2 = iloc >> 5, ip = iloc & 31;
        int row0 = (iw2 * 2 + 0) * 32 + ip;
        int row1 = (iw2 * 2 + 1) * 32 + ip;
        const float* r0 = Obuf + row0 * 65;
        const float* r1 = Obuf + row1 * 65;
        float2 s0 = ml[row0], s1 = ml[row1];
        float mm = fmaxf(s0.x, s1.x);
        float a0 = __builtin_amdgcn_exp2f(s0.x - mm);
        float a1 = __builtin_amdgcn_exp2f(s1.x - mm);
        float l  = s0.y * a0 + s1.y * a1;
        float c0 = a0 / l, c1 = a1 / l;
        unsigned pk[8];
        #pragma unroll
        for (int jj = 0; jj < 8; jj++) {
            float v0 = r0[cq * 16 + 2*jj    ] * c0 + r1[cq * 16 + 2*jj    ] * c1;
            float v1 = r0[cq * 16 + 2*jj + 1] * c0 + r1[cq * 16 + 2*jj + 1] * c1;
            pk[jj] = (unsigned)f2bf(v0) | ((unsigned)f2bf(v1) << 16);
        }
        unsigned short* dst = ao + ((size_t)b * HW + i0 + iloc) * 256 + hh * 64 + cq * 16;
        *(uint4*)dst       = make_uint4(pk[0], pk[1], pk[2], pk[3]);
        *(uint4*)(dst + 8) = make_uint4(pk[4], pk[5], pk[6], pk[7]);
    }
}

extern "C" void kernel_launch(void* const* d_in, const int* in_sizes, int n_in,
                              void* d_out, int out_size, void* d_ws, size_t ws_size,
                              hipStream_t stream) {
    const float* x      = (const float*)d_in[0];
    const float* gamma  = (const float*)d_in[1];
    const float* beta   = (const float*)d_in[2];
    const float* w_qkv  = (const float*)d_in[3];
    const float* b_qkv  = (const float*)d_in[4];
    const float* w_proj = (const float*)d_in[5];
    const float* b_proj = (const float*)d_in[6];
    float* out = (float*)d_out;

    // ws: stats 256f | part 1024 float2 | qt,kt,vv,ao (4 x 4M ushorts = 32MB) | wt,wpt bf16
    float* stats = (float*)d_ws;
    float2* part = (float2*)(stats + 256);
    unsigned short* qt  = (unsigned short*)(stats + 256 + 2048);
    unsigned short* kt  = qt + (size_t)4194304;
    unsigned short* vv  = kt + (size_t)4194304;
    unsigned short* ao  = vv + (size_t)4194304;
    unsigned short* wt  = ao + (size_t)4194304;
    unsigned short* wpt = wt + 196608;

    wconv_k<<<256, 256, 0, stream>>>(w_qkv, w_proj, wt, wpt);
    gn_stats_part_k<<<1024, 256, 0, stream>>>(x, part);
    gn_stats_fin_k<<<1, 64, 0, stream>>>(part, stats);
    gemm_qkv_fused_k<<<dim3(64, NB), 256, 0, stream>>>(wt, x, gamma, beta, stats, b_qkv, qt, kt, vv);
    attn_k<<<dim3(64, NH, NB), 256, 0, stream>>>(qt, kt, vv, ao);
    gemm_proj_mfma_k<<<dim3(64, 4, NB), 256, 0, stream>>>(wpt, ao, b_proj, x, out);
}